// Round 4
// baseline (261.068 us; speedup 1.0000x reference)
//
#include <hip/hip_runtime.h>
#include <stdint.h>

// Disable FP contraction file-wide: the d2 <= R2 inclusion test is a discrete
// decision that must match the reference's fp32 mul+add rounding (XLA/numpy do
// not fuse into fma across ops).
#pragma clang fp contract(off)

#define S 256
#define NPTS 100000
#define BATCH 4
#define CCH 64
#define K 8
#define CAP 20   // per-pixel candidate list capacity (lambda~3.4, P(>20)~1e-10)

static constexpr float R2 = 0.01171875f * 0.01171875f;  // (1.5/256*2)^2, exact
static constexpr unsigned long long SENT = 0xFFFFFFFFFFFFFFFFULL;

// ===========================================================================
// Stage 1 -- Scatter: 16 THREADS PER POINT (one per 4x4 cell), append-list
// commit. PROVEN in round 1. (Round 2's 1-thread/point variant regressed
// +25 us: the 16-way split gives 16x more independent atomic+store chains
// per wave for latency hiding, not just shorter cascades.)
// key = (z_bits << 32) | point_idx -- ascending (z, idx) == reference
// lexsort rank; keys unique, so deferred selection reproduces the reference
// top-K exactly regardless of commit order.
// ===========================================================================
__global__ __launch_bounds__(256) void scatter_list_kernel(
        const float* __restrict__ pts,
        unsigned int* __restrict__ counts,
        unsigned long long* __restrict__ lists) {
    int gid = blockIdx.x * blockDim.x + threadIdx.x;
    if (gid >= BATCH * NPTS * 16) return;
    int cell = gid & 15;
    int pid  = gid >> 4;
    int b = pid / NPTS;
    int n = pid - b * NPTS;

    const float* p = pts + (size_t)pid * 3;
    float x = -p[0];                 // reference flips x,y signs
    float y = -p[1];
    float z = p[2];
    if (!(z >= 0.0f)) return;

    float px = (1.0f - x) * 128.0f - 0.5f;   // (1-x)*(S/2) - 0.5
    float py = (1.0f - y) * 128.0f - 0.5f;
    int cj0 = (int)floorf(px);
    int ci0 = (int)floorf(py);

    int ci = ci0 - 1 + (cell >> 2);
    int cj = cj0 - 1 + (cell & 3);
    if (ci < 0 || ci >= S || cj < 0 || cj >= S) return;

    float cy = 1.0f - 2.0f * ((float)ci + 0.5f) / 256.0f;
    float cx = 1.0f - 2.0f * ((float)cj + 0.5f) / 256.0f;
    float dy = cy - y;
    float dx = cx - x;
    float d2 = dy * dy + dx * dx;
    if (!(d2 <= R2)) return;

    unsigned long long key =
        ((unsigned long long)__float_as_uint(z) << 32) | (unsigned int)n;
    size_t base = (size_t)b * (S * S) + (size_t)(ci * S + cj);
    unsigned int old = atomicAdd(&counts[base], 1u);
    if (old < CAP) lists[base * CAP + old] = key;
}

// ===========================================================================
// Stage 2 -- Select: ONE THREAD PER PIXEL, standalone kernel.
// Why standalone: inside blend, the count-load -> list-load -> sort chain ran
// serialized on wave 0 of each of 4096 blocks (~31 us of blend's 71.5 us
// critical path; R0's dense-key blend without it ran ~40 us). Here the same
// chain is paid once by 262k independent threads at full occupancy:
//   - counts: consecutive threads -> consecutive 4B, coalesced.
//   - lists:  each thread streams its own contiguous 160B row; a wave covers
//     10 KB contiguous. Conditional-load structure copied from the proven
//     round-2 phase 0 (short live ranges -- 52 VGPR, no spill; round 3's
//     unconditional variant spilled: VGPR 28, +8 MB scratch writes).
//   - output: 8 sorted keys = 64B contiguous per thread, coalesced.
// Output buffer == the converged state of the old atomicMin-cascade slots,
// so the proven dense blend_kernel consumes it unchanged.
// ===========================================================================
__global__ __launch_bounds__(256) void select_topk_kernel(
        const unsigned int* __restrict__ counts,
        const unsigned long long* __restrict__ lists,
        unsigned long long* __restrict__ keys) {
    int pix = blockIdx.x * blockDim.x + threadIdx.x;
    if (pix >= BATCH * S * S) return;

    int c = (int)counts[pix];
    if (c > CAP) c = CAP;
    const ulonglong2* lp2 =
        reinterpret_cast<const ulonglong2*>(lists + (size_t)pix * CAP);

    unsigned long long v[CAP];
#pragma unroll
    for (int j = 0; j < CAP / 2; ++j) {
        unsigned long long lo = SENT, hi = SENT;
        if (2 * j < c) { ulonglong2 t = lp2[j]; lo = t.x; hi = t.y; }
        v[2 * j] = lo;
        v[2 * j + 1] = hi;
    }
#pragma unroll
    for (int j = 0; j < CAP; ++j)
        if (j >= c) v[j] = SENT;   // mask garbage beyond count

    // partial selection sort: v[0..7] become the 8 smallest, ascending
#pragma unroll
    for (int i = 0; i < K; ++i) {
#pragma unroll
        for (int j = i + 1; j < CAP; ++j) {
            unsigned long long a = v[i], q = v[j];
            v[i] = a < q ? a : q;
            v[j] = a < q ? q : a;
        }
    }

    ulonglong2* kout = reinterpret_cast<ulonglong2*>(keys + (size_t)pix * K);
#pragma unroll
    for (int k = 0; k < K / 2; ++k) {
        ulonglong2 t;
        t.x = v[2 * k];
        t.y = v[2 * k + 1];
        kout[k] = t;
    }
}

// ===========================================================================
// Stage 3 -- Blend: dense sorted-key consumer. PROVEN form from round 0
// (~40 us): block = (b, row h, 64-pixel segment).
//   Phase 1: decode keys -> alpha (d2 recomputed from point coords), LDS.
//   Phase 2: exclusive cumprod of (1-alpha) -> weights (tid<64).
//   Phase 3: k-major loop (uniform trip = wave max count): 16 independent
//            gathers in flight per iteration; invalid slots gather clamped
//            idx 0 (L1-resident row -> ~free) with weight 0.
//   Phase 4: lane c stores 16 contiguous w-floats (4x float4 = 64B line).
// LDS arrays padded to K+1=9 to break the 16-way cumprod bank conflict.
// ===========================================================================
__global__ __launch_bounds__(256) void blend_kernel(
        const float* __restrict__ pts,
        const float* __restrict__ feat,
        const unsigned long long* __restrict__ keys,
        float* __restrict__ out) {
    int seg = blockIdx.x;   // 0..3  (w segment)
    int h   = blockIdx.y;   // 0..255
    int b   = blockIdx.z;   // 0..3
    int tid = threadIdx.x;
    int w0  = seg * 64;

    __shared__ float s_alpha[64][K + 1];
    __shared__ float s_wgt[64][K + 1];
    __shared__ int   s_idx[64][K + 1];
    __shared__ int   s_cnt[64];

    const unsigned long long* kb =
        keys + ((size_t)b * S * S + (size_t)h * S + w0) * K;
    const float* pb = pts + (size_t)b * NPTS * 3;

    for (int e = tid; e < 64 * K; e += 256) {
        int p = e >> 3;
        int k = e & 7;
        unsigned long long key = kb[(size_t)p * K + k];
        float alpha = 0.0f;
        int idx = -1;
        if (key != SENT) {
            idx = (int)(unsigned int)(key & 0xFFFFFFFFULL);
            float x = -pb[(size_t)idx * 3 + 0];
            float y = -pb[(size_t)idx * 3 + 1];
            int w = w0 + p;
            float cy = 1.0f - 2.0f * ((float)h + 0.5f) / 256.0f;
            float cx = 1.0f - 2.0f * ((float)w + 0.5f) / 256.0f;
            float dy = cy - y;
            float dx = cx - x;
            float d2 = dy * dy + dx * dx;
            float dist = d2 / R2;
            dist = fminf(fmaxf(dist, 0.001f), 1.0f);
            alpha = 1.0f - sqrtf(dist);     // gamma = 1 -> **0.5
        }
        s_alpha[p][k] = alpha;
        s_idx[p][k] = idx;
    }
    __syncthreads();

    if (tid < 64) {
        float t = 1.0f;
        int cnt = 0;
        for (int k = 0; k < K; ++k) {
            int raw = s_idx[tid][k];
            float a = s_alpha[tid][k];
            s_wgt[tid][k] = a * t;
            t *= (1.0f - a);
            if (raw >= 0) cnt = k + 1;
            s_idx[tid][k] = raw < 0 ? 0 : raw;
        }
        s_cnt[tid] = cnt;
    }
    __syncthreads();

    int wave = tid >> 6;    // 0..3
    int lane = tid & 63;    // channel
    int pbase = wave * 16;

    int kmax = 0;
#pragma unroll
    for (int i = 0; i < 16; ++i) {
        int c = s_cnt[pbase + i];
        kmax = c > kmax ? c : kmax;
    }

    float acc[16];
#pragma unroll
    for (int i = 0; i < 16; ++i) acc[i] = 0.0f;

    const float* fbl = feat + (size_t)b * NPTS * CCH + lane;
    for (int k = 0; k < kmax; ++k) {
        float v[16];
#pragma unroll
        for (int i = 0; i < 16; ++i) {
            int idx = s_idx[pbase + i][k];          // wave-uniform broadcast
            v[i] = fbl[(size_t)idx << 6];
        }
#pragma unroll
        for (int i = 0; i < 16; ++i) {
            acc[i] += s_wgt[pbase + i][k] * v[i];
        }
    }

    // Phase 4: transposed store, one 64B line per lane (4x float4)
    size_t obase = (((size_t)b * CCH + lane) * S + h) * S + (size_t)(w0 + pbase);
    float4* o4 = (float4*)(out + obase);
#pragma unroll
    for (int q = 0; q < 4; ++q) {
        o4[q] = make_float4(acc[4 * q + 0], acc[4 * q + 1],
                            acc[4 * q + 2], acc[4 * q + 3]);
    }
}

// ===========================================================================
// FALLBACK PATH (proven): sorted atomicMin cascade into dense per-pixel key
// slots; feeds the same blend_kernel. Used only if ws_size is too small for
// the append lists.
// ===========================================================================
__global__ __launch_bounds__(256) void scatter_kernel(
        const float* __restrict__ pts,
        unsigned long long* __restrict__ keys) {
    int gid = blockIdx.x * blockDim.x + threadIdx.x;
    if (gid >= BATCH * NPTS * 16) return;
    int cell = gid & 15;
    int pid  = gid >> 4;
    int b = pid / NPTS;
    int n = pid - b * NPTS;

    const float* p = pts + (size_t)pid * 3;
    float x = -p[0];
    float y = -p[1];
    float z = p[2];
    if (!(z >= 0.0f)) return;

    float px = (1.0f - x) * 128.0f - 0.5f;
    float py = (1.0f - y) * 128.0f - 0.5f;
    int cj0 = (int)floorf(px);
    int ci0 = (int)floorf(py);

    int ci = ci0 - 1 + (cell >> 2);
    int cj = cj0 - 1 + (cell & 3);
    if (ci < 0 || ci >= S || cj < 0 || cj >= S) return;

    float cy = 1.0f - 2.0f * ((float)ci + 0.5f) / 256.0f;
    float cx = 1.0f - 2.0f * ((float)cj + 0.5f) / 256.0f;
    float dy = cy - y;
    float dx = cx - x;
    float d2 = dy * dy + dx * dx;
    if (!(d2 <= R2)) return;

    unsigned long long key =
        ((unsigned long long)__float_as_uint(z) << 32) | (unsigned int)n;
    unsigned long long* slot =
        keys + ((size_t)b * S * S + (size_t)(ci * S + cj)) * K;

    if (slot[K - 1] < key) return;

    for (int s = 0; s < K; ++s) {
        if (key == SENT) break;
        unsigned long long old = atomicMin(&slot[s], key);
        key = old > key ? old : key;
    }
}

extern "C" void kernel_launch(void* const* d_in, const int* in_sizes, int n_in,
                              void* d_out, int out_size, void* d_ws, size_t ws_size,
                              hipStream_t stream) {
    const float* pts  = (const float*)d_in[0];
    const float* feat = (const float*)d_in[1];
    float* out = (float*)d_out;

    size_t cnt_bytes  = (size_t)BATCH * S * S * sizeof(unsigned int);      // 1 MB
    size_t list_bytes = (size_t)BATCH * S * S * CAP * sizeof(unsigned long long); // 42 MB
    size_t key_bytes  = (size_t)BATCH * S * S * K * sizeof(unsigned long long);   // 16.8 MB

    if (ws_size >= cnt_bytes + list_bytes + key_bytes) {
        // list path: 1-atomic scatter -> parallel select -> dense blend
        unsigned int* counts = (unsigned int*)d_ws;
        unsigned long long* lists =
            (unsigned long long*)((char*)d_ws + cnt_bytes);
        unsigned long long* dkeys =
            (unsigned long long*)((char*)d_ws + cnt_bytes + list_bytes);
        hipMemsetAsync(counts, 0, cnt_bytes, stream);

        int total = BATCH * NPTS * 16;
        scatter_list_kernel<<<(total + 255) / 256, 256, 0, stream>>>(
            pts, counts, lists);

        int npix = BATCH * S * S;
        select_topk_kernel<<<(npix + 255) / 256, 256, 0, stream>>>(
            counts, lists, dkeys);

        dim3 grid(S / 64, S, BATCH);
        blend_kernel<<<grid, 256, 0, stream>>>(pts, feat, dkeys, out);
    } else {
        // fallback: proven sorted-cascade path
        unsigned long long* keys = (unsigned long long*)d_ws;
        hipMemsetAsync(keys, 0xFF, key_bytes, stream);

        int total = BATCH * NPTS * 16;
        scatter_kernel<<<(total + 255) / 256, 256, 0, stream>>>(pts, keys);

        dim3 grid(S / 64, S, BATCH);
        blend_kernel<<<grid, 256, 0, stream>>>(pts, feat, keys, out);
    }
}

// Round 5
// 248.613 us; speedup vs baseline: 1.0501x; 1.0501x over previous
//
#include <hip/hip_runtime.h>
#include <stdint.h>

// Disable FP contraction file-wide: the d2 <= R2 inclusion test is a discrete
// decision that must match the reference's fp32 mul+add rounding (XLA/numpy do
// not fuse into fma across ops).
#pragma clang fp contract(off)

#define S 256
#define NPTS 100000
#define BATCH 4
#define CCH 64
#define K 8
#define CAP 20   // per-pixel candidate list capacity (lambda~3.4, P(>20)~1e-10)

static constexpr float R2 = 0.01171875f * 0.01171875f;  // (1.5/256*2)^2, exact
static constexpr unsigned long long SENT = 0xFFFFFFFFFFFFFFFFULL;

// ===========================================================================
// Stage 1 -- Scatter: 16 THREADS PER POINT (one per 4x4 cell), append-list
// commit. PROVEN in round 1 (242.8 us total). Round 2's 1-thread/point
// variant regressed +25 us: the 16-way split gives 16x more independent
// atomic+store chains per wave for latency hiding, not just shorter chains.
// key = (z_bits << 32) | point_idx -- ascending (z, idx) == reference
// lexsort rank; keys unique, so deferred selection reproduces the reference
// top-K exactly regardless of commit order.
// ===========================================================================
__global__ __launch_bounds__(256) void scatter_list_kernel(
        const float* __restrict__ pts,
        unsigned int* __restrict__ counts,
        unsigned long long* __restrict__ lists) {
    int gid = blockIdx.x * blockDim.x + threadIdx.x;
    if (gid >= BATCH * NPTS * 16) return;
    int cell = gid & 15;
    int pid  = gid >> 4;
    int b = pid / NPTS;
    int n = pid - b * NPTS;

    const float* p = pts + (size_t)pid * 3;
    float x = -p[0];                 // reference flips x,y signs
    float y = -p[1];
    float z = p[2];
    if (!(z >= 0.0f)) return;

    float px = (1.0f - x) * 128.0f - 0.5f;   // (1-x)*(S/2) - 0.5
    float py = (1.0f - y) * 128.0f - 0.5f;
    int cj0 = (int)floorf(px);
    int ci0 = (int)floorf(py);

    int ci = ci0 - 1 + (cell >> 2);
    int cj = cj0 - 1 + (cell & 3);
    if (ci < 0 || ci >= S || cj < 0 || cj >= S) return;

    float cy = 1.0f - 2.0f * ((float)ci + 0.5f) / 256.0f;
    float cx = 1.0f - 2.0f * ((float)cj + 0.5f) / 256.0f;
    float dy = cy - y;
    float dx = cx - x;
    float d2 = dy * dy + dx * dx;
    if (!(d2 <= R2)) return;

    unsigned long long key =
        ((unsigned long long)__float_as_uint(z) << 32) | (unsigned int)n;
    size_t base = (size_t)b * (S * S) + (size_t)(ci * S + cj);
    unsigned int old = atomicAdd(&counts[base], 1u);
    if (old < CAP) lists[base * CAP + old] = key;
}

// compare-swap (ascending) and sorted-insert for the streaming top-8.
// Inserting SENT is a no-op (SENT >= t7 always), so padding needs no mask.
#define CSW(a, b) do {                                        \
        unsigned long long _lo = (a) < (b) ? (a) : (b);       \
        unsigned long long _hi = (a) < (b) ? (b) : (a);       \
        (a) = _lo; (b) = _hi;                                 \
    } while (0)
#define INSERT8(x) do {                                       \
        unsigned long long _x = (x);                          \
        t7 = t7 < _x ? t7 : _x;                               \
        CSW(t6, t7); CSW(t5, t6); CSW(t4, t5); CSW(t3, t4);   \
        CSW(t2, t3); CSW(t1, t2); CSW(t0, t1);                \
    } while (0)

// ===========================================================================
// Stage 2 -- Blend (fused select). PROVEN round-1 skeleton (71.5 us) with
// two fixes:
//  (a) Phase 0 top-K via STREAMING 8-REGISTER INSERTION instead of a v[20]
//      register array + partial selection sort. The array form is what the
//      allocator keeps spilling (R3: VGPR 28 + 8MB scratch writes; R4's
//      standalone select ~48 us): 8 named u64 regs cannot spill, and a
//      wave-uniform early exit caps work at ceil(cmax/2) iterations.
//      Resulting t0..t7 = 8 smallest keys ascending == reference lexsort.
//  (b) XCD-CHUNKED block swizzle: logical = (blk&7)*512 + (blk>>3) gives
//      each XCD 128 contiguous image rows of one batch. Feature rows are
//      re-gathered by up to ~8 neighboring pixel-blocks; with the chunk,
//      those re-reads hit the XCD's 4MB L2 (region working set ~4MB)
//      instead of L3. Perf heuristic only -- correctness mapping-independent.
// Block = 256 threads handles (b, row h, 64-pixel segment), as before.
// LDS arrays padded to K+1=9 to break the 16-way cumprod bank conflict.
// ===========================================================================
__global__ __launch_bounds__(256) void blend_list_kernel(
        const float* __restrict__ pts,
        const float* __restrict__ feat,
        const unsigned int* __restrict__ counts,
        const unsigned long long* __restrict__ lists,
        float* __restrict__ out) {
    int blk = blockIdx.x;                       // 0..4095
    int logical = (blk & 7) * 512 + (blk >> 3); // XCD chunk (4096 % 8 == 0)
    int seg = logical & 3;                      // 0..3  (w segment)
    int h   = (logical >> 2) & 255;             // 0..255
    int b   = logical >> 10;                    // 0..3
    int tid = threadIdx.x;
    int w0  = seg * 64;

    __shared__ float s_alpha[64][K + 1];
    __shared__ float s_wgt[64][K + 1];
    __shared__ int   s_idx[64][K + 1];
    __shared__ int   s_cnt[64];
    __shared__ unsigned long long s_key[64][K];

    const float* pb = pts + (size_t)b * NPTS * 3;

    // Phase 0: wave 0, one pixel per lane; streaming top-8 insertion.
    if (tid < 64) {
        size_t base = (size_t)b * (S * S) + (size_t)h * S + (size_t)(w0 + tid);
        int c = (int)counts[base];
        if (c > CAP) c = CAP;
        const ulonglong2* lp2 =
            reinterpret_cast<const ulonglong2*>(lists + base * (size_t)CAP);

        unsigned long long t0 = SENT, t1 = SENT, t2 = SENT, t3 = SENT;
        unsigned long long t4 = SENT, t5 = SENT, t6 = SENT, t7 = SENT;

        for (int j = 0; j < CAP / 2; ++j) {
            if (!__any(2 * j < c)) break;       // wave-uniform early exit
            unsigned long long lo = SENT, hi = SENT;
            if (2 * j < c) {
                ulonglong2 t = lp2[j];
                lo = t.x;
                hi = (2 * j + 1 < c) ? t.y : SENT;  // mask odd-count garbage
            }
            INSERT8(lo);
            INSERT8(hi);
        }

        s_key[tid][0] = t0; s_key[tid][1] = t1;
        s_key[tid][2] = t2; s_key[tid][3] = t3;
        s_key[tid][4] = t4; s_key[tid][5] = t5;
        s_key[tid][6] = t6; s_key[tid][7] = t7;
        s_cnt[tid] = c < K ? c : K;
    }
    __syncthreads();

    // Phase 1: 512 entries, 2 per thread: decode key -> alpha
    for (int e = tid; e < 64 * K; e += 256) {
        int p = e >> 3;
        int k = e & 7;
        unsigned long long key = s_key[p][k];
        float alpha = 0.0f;
        int idx = 0;
        if (key != SENT) {
            idx = (int)(unsigned int)(key & 0xFFFFFFFFULL);
            float x = -pb[(size_t)idx * 3 + 0];
            float y = -pb[(size_t)idx * 3 + 1];
            int w = w0 + p;
            float cy = 1.0f - 2.0f * ((float)h + 0.5f) / 256.0f;
            float cx = 1.0f - 2.0f * ((float)w + 0.5f) / 256.0f;
            float dy = cy - y;
            float dx = cx - x;
            float d2 = dy * dy + dx * dx;
            float dist = d2 / R2;
            dist = fminf(fmaxf(dist, 0.001f), 1.0f);
            alpha = 1.0f - sqrtf(dist);     // gamma = 1 -> **0.5
        }
        s_alpha[p][k] = alpha;
        s_idx[p][k] = idx;
    }
    __syncthreads();

    // Phase 2: exclusive cumprod of (1 - alpha) -> weights
    if (tid < 64) {
        float t = 1.0f;
#pragma unroll
        for (int k = 0; k < K; ++k) {
            float a = s_alpha[tid][k];      // 0 for invalid slots
            s_wgt[tid][k] = a * t;
            t *= (1.0f - a);
        }
    }
    __syncthreads();

    // Phase 3: k-major accumulate, 16 independent gathers per k, unroll 2.
    // Invalid slots gather clamped idx 0 (L1-resident row) with weight 0.
    int wave = tid >> 6;    // 0..3
    int lane = tid & 63;    // channel
    int pbase = wave * 16;

    int kmax = 0;
#pragma unroll
    for (int i = 0; i < 16; ++i) {
        int c = s_cnt[pbase + i];
        kmax = c > kmax ? c : kmax;
    }

    float acc[16];
#pragma unroll
    for (int i = 0; i < 16; ++i) acc[i] = 0.0f;

    const float* fbl = feat + (size_t)b * NPTS * CCH + lane;
#pragma unroll 2
    for (int k = 0; k < kmax; ++k) {
        float v[16];
#pragma unroll
        for (int i = 0; i < 16; ++i) {
            int idx = s_idx[pbase + i][k];          // wave-uniform broadcast
            v[i] = fbl[(size_t)idx << 6];
        }
#pragma unroll
        for (int i = 0; i < 16; ++i) {
            acc[i] += s_wgt[pbase + i][k] * v[i];
        }
    }

    // Phase 4: transposed store, one 64B line per lane (4x float4)
    size_t obase = (((size_t)b * CCH + lane) * S + h) * S + (size_t)(w0 + pbase);
    float4* o4 = (float4*)(out + obase);
#pragma unroll
    for (int q = 0; q < 4; ++q) {
        o4[q] = make_float4(acc[4 * q + 0], acc[4 * q + 1],
                            acc[4 * q + 2], acc[4 * q + 3]);
    }
}

// ===========================================================================
// FALLBACK PATH (unchanged, proven): sorted atomicMin cascade into dense
// per-pixel key slots + original dense blend. Used only if ws_size is too
// small for the append lists.
// ===========================================================================
__global__ __launch_bounds__(256) void scatter_kernel(
        const float* __restrict__ pts,
        unsigned long long* __restrict__ keys) {
    int gid = blockIdx.x * blockDim.x + threadIdx.x;
    if (gid >= BATCH * NPTS * 16) return;
    int cell = gid & 15;
    int pid  = gid >> 4;
    int b = pid / NPTS;
    int n = pid - b * NPTS;

    const float* p = pts + (size_t)pid * 3;
    float x = -p[0];
    float y = -p[1];
    float z = p[2];
    if (!(z >= 0.0f)) return;

    float px = (1.0f - x) * 128.0f - 0.5f;
    float py = (1.0f - y) * 128.0f - 0.5f;
    int cj0 = (int)floorf(px);
    int ci0 = (int)floorf(py);

    int ci = ci0 - 1 + (cell >> 2);
    int cj = cj0 - 1 + (cell & 3);
    if (ci < 0 || ci >= S || cj < 0 || cj >= S) return;

    float cy = 1.0f - 2.0f * ((float)ci + 0.5f) / 256.0f;
    float cx = 1.0f - 2.0f * ((float)cj + 0.5f) / 256.0f;
    float dy = cy - y;
    float dx = cx - x;
    float d2 = dy * dy + dx * dx;
    if (!(d2 <= R2)) return;

    unsigned long long key =
        ((unsigned long long)__float_as_uint(z) << 32) | (unsigned int)n;
    unsigned long long* slot =
        keys + ((size_t)b * S * S + (size_t)(ci * S + cj)) * K;

    if (slot[K - 1] < key) return;

    for (int s = 0; s < K; ++s) {
        if (key == SENT) break;
        unsigned long long old = atomicMin(&slot[s], key);
        key = old > key ? old : key;
    }
}

__global__ __launch_bounds__(256) void blend_kernel(
        const float* __restrict__ pts,
        const float* __restrict__ feat,
        const unsigned long long* __restrict__ keys,
        float* __restrict__ out) {
    int seg = blockIdx.x;
    int h   = blockIdx.y;
    int b   = blockIdx.z;
    int tid = threadIdx.x;
    int w0  = seg * 64;

    __shared__ float s_alpha[64][K + 1];
    __shared__ float s_wgt[64][K + 1];
    __shared__ int   s_idx[64][K + 1];
    __shared__ int   s_cnt[64];

    const unsigned long long* kb =
        keys + ((size_t)b * S * S + (size_t)h * S + w0) * K;
    const float* pb = pts + (size_t)b * NPTS * 3;

    for (int e = tid; e < 64 * K; e += 256) {
        int p = e >> 3;
        int k = e & 7;
        unsigned long long key = kb[(size_t)p * K + k];
        float alpha = 0.0f;
        int idx = -1;
        if (key != SENT) {
            idx = (int)(unsigned int)(key & 0xFFFFFFFFULL);
            float x = -pb[(size_t)idx * 3 + 0];
            float y = -pb[(size_t)idx * 3 + 1];
            int w = w0 + p;
            float cy = 1.0f - 2.0f * ((float)h + 0.5f) / 256.0f;
            float cx = 1.0f - 2.0f * ((float)w + 0.5f) / 256.0f;
            float dy = cy - y;
            float dx = cx - x;
            float d2 = dy * dy + dx * dx;
            float dist = d2 / R2;
            dist = fminf(fmaxf(dist, 0.001f), 1.0f);
            alpha = 1.0f - sqrtf(dist);
        }
        s_alpha[p][k] = alpha;
        s_idx[p][k] = idx;
    }
    __syncthreads();

    if (tid < 64) {
        float t = 1.0f;
        int cnt = 0;
        for (int k = 0; k < K; ++k) {
            int raw = s_idx[tid][k];
            float a = s_alpha[tid][k];
            s_wgt[tid][k] = a * t;
            t *= (1.0f - a);
            if (raw >= 0) cnt = k + 1;
            s_idx[tid][k] = raw < 0 ? 0 : raw;
        }
        s_cnt[tid] = cnt;
    }
    __syncthreads();

    int wave = tid >> 6;
    int lane = tid & 63;
    int pbase = wave * 16;

    int kmax = 0;
#pragma unroll
    for (int i = 0; i < 16; ++i) {
        int c = s_cnt[pbase + i];
        kmax = c > kmax ? c : kmax;
    }

    float acc[16];
#pragma unroll
    for (int i = 0; i < 16; ++i) acc[i] = 0.0f;

    const float* fbl = feat + (size_t)b * NPTS * CCH + lane;
    for (int k = 0; k < kmax; ++k) {
        float v[16];
#pragma unroll
        for (int i = 0; i < 16; ++i) {
            int idx = s_idx[pbase + i][k];
            v[i] = fbl[(size_t)idx << 6];
        }
#pragma unroll
        for (int i = 0; i < 16; ++i) {
            acc[i] += s_wgt[pbase + i][k] * v[i];
        }
    }

    size_t obase = (((size_t)b * CCH + lane) * S + h) * S + (size_t)(w0 + pbase);
    float4* o4 = (float4*)(out + obase);
#pragma unroll
    for (int q = 0; q < 4; ++q) {
        o4[q] = make_float4(acc[4 * q + 0], acc[4 * q + 1],
                            acc[4 * q + 2], acc[4 * q + 3]);
    }
}

extern "C" void kernel_launch(void* const* d_in, const int* in_sizes, int n_in,
                              void* d_out, int out_size, void* d_ws, size_t ws_size,
                              hipStream_t stream) {
    const float* pts  = (const float*)d_in[0];
    const float* feat = (const float*)d_in[1];
    float* out = (float*)d_out;

    size_t cnt_bytes  = (size_t)BATCH * S * S * sizeof(unsigned int);      // 1 MB
    size_t list_bytes = (size_t)BATCH * S * S * CAP * sizeof(unsigned long long); // 42 MB
    size_t key_bytes  = (size_t)BATCH * S * S * K * sizeof(unsigned long long);   // 16.8 MB

    if (ws_size >= cnt_bytes + list_bytes) {
        // list path: 1-atomic scatter -> fused select+blend
        unsigned int* counts = (unsigned int*)d_ws;
        unsigned long long* lists =
            (unsigned long long*)((char*)d_ws + cnt_bytes);
        hipMemsetAsync(counts, 0, cnt_bytes, stream);

        int total = BATCH * NPTS * 16;
        scatter_list_kernel<<<(total + 255) / 256, 256, 0, stream>>>(
            pts, counts, lists);

        blend_list_kernel<<<4096, 256, 0, stream>>>(pts, feat, counts, lists, out);
    } else {
        // fallback: proven sorted-cascade path
        unsigned long long* keys = (unsigned long long*)d_ws;
        hipMemsetAsync(keys, 0xFF, key_bytes, stream);

        int total = BATCH * NPTS * 16;
        scatter_kernel<<<(total + 255) / 256, 256, 0, stream>>>(pts, keys);

        dim3 grid(S / 64, S, BATCH);
        blend_kernel<<<grid, 256, 0, stream>>>(pts, feat, keys, out);
    }
}

// Round 6
// 244.702 us; speedup vs baseline: 1.0669x; 1.0160x over previous
//
#include <hip/hip_runtime.h>
#include <stdint.h>

// Disable FP contraction file-wide: the d2 <= R2 inclusion test is a discrete
// decision that must match the reference's fp32 mul+add rounding (XLA/numpy do
// not fuse into fma across ops).
#pragma clang fp contract(off)

#define S 256
#define NPTS 100000
#define BATCH 4
#define CCH 64
#define K 8
#define CAP 20   // per-pixel candidate list capacity (lambda<=3.4, P(>20)~1e-10)

static constexpr float R2 = 0.01171875f * 0.01171875f;  // (1.5/256*2)^2, exact
static constexpr unsigned long long SENT = 0xFFFFFFFFFFFFFFFFULL;

// ===========================================================================
// Stage 1 -- Scatter: 16 THREADS PER POINT (one per 4x4 cell), append-list
// commit. PROVEN in round 1 (242.8 us total; ~15 us standalone). Round 2's
// 1-thread/point variant regressed +25 us: the 16-way split gives 16x more
// independent atomic+store chains per wave for latency hiding.
// key = (z_bits << 32) | point_idx -- ascending (z, idx) == reference
// lexsort rank; keys unique, so deferred selection reproduces the reference
// top-K exactly regardless of commit order.
// ===========================================================================
__global__ __launch_bounds__(256) void scatter_list_kernel(
        const float* __restrict__ pts,
        unsigned int* __restrict__ counts,
        unsigned long long* __restrict__ lists) {
    int gid = blockIdx.x * blockDim.x + threadIdx.x;
    if (gid >= BATCH * NPTS * 16) return;
    int cell = gid & 15;
    int pid  = gid >> 4;
    int b = pid / NPTS;
    int n = pid - b * NPTS;

    const float* p = pts + (size_t)pid * 3;
    float x = -p[0];                 // reference flips x,y signs
    float y = -p[1];
    float z = p[2];
    if (!(z >= 0.0f)) return;

    float px = (1.0f - x) * 128.0f - 0.5f;   // (1-x)*(S/2) - 0.5
    float py = (1.0f - y) * 128.0f - 0.5f;
    int cj0 = (int)floorf(px);
    int ci0 = (int)floorf(py);

    int ci = ci0 - 1 + (cell >> 2);
    int cj = cj0 - 1 + (cell & 3);
    if (ci < 0 || ci >= S || cj < 0 || cj >= S) return;

    float cy = 1.0f - 2.0f * ((float)ci + 0.5f) / 256.0f;
    float cx = 1.0f - 2.0f * ((float)cj + 0.5f) / 256.0f;
    float dy = cy - y;
    float dx = cx - x;
    float d2 = dy * dy + dx * dx;
    if (!(d2 <= R2)) return;

    unsigned long long key =
        ((unsigned long long)__float_as_uint(z) << 32) | (unsigned int)n;
    size_t base = (size_t)b * (S * S) + (size_t)(ci * S + cj);
    unsigned int old = atomicAdd(&counts[base], 1u);
    if (old < CAP) lists[base * CAP + old] = key;
}

// compare-swap (ascending) and sorted-insert for the streaming top-8.
// Inserting SENT is a no-op (SENT >= t7 always), so masked slots need no
// special handling beyond the cndmask that produced them.
#define CSW(a, b) do {                                        \
        unsigned long long _lo = (a) < (b) ? (a) : (b);       \
        unsigned long long _hi = (a) < (b) ? (b) : (a);       \
        (a) = _lo; (b) = _hi;                                 \
    } while (0)
#define INSERT8(x) do {                                       \
        unsigned long long _x = (x);                          \
        t7 = t7 < _x ? t7 : _x;                               \
        CSW(t6, t7); CSW(t5, t6); CSW(t4, t5); CSW(t3, t4);   \
        CSW(t2, t3); CSW(t1, t2); CSW(t0, t1);                \
    } while (0)
// masked insert of pair j from named register q (branch-free: cndmask)
#define PAIR(j, q) do {                                                   \
        INSERT8((2 * (j)     < c) ? (q).x : SENT);                        \
        INSERT8((2 * (j) + 1 < c) ? (q).y : SENT);                        \
    } while (0)

// ===========================================================================
// Stage 2 -- Blend (fused select).
// ROUND-5 POST-MORTEM: phase 0 cost ~5.8 us/block = ~10 SERIAL memory
// round-trips -- the early-exit `break` made each pair-load's issue
// control-dependent on the previous iteration (R1's indexed-array variant
// had the same serialized signature). FIX: all 10 pair-loads + the count
// load are UNCONDITIONAL, UNROLLED, into NAMED ulonglong2 registers -- 11
// independent loads issue back-to-back (1 round-trip), then branch-free
// cndmask masking (vs count) feeds the 8-register insertion network.
// No array -> no scratch; no break -> no serialization.
// Extra ~30 MB of tail-of-list reads are L2-resident (scatter just wrote
// them; XCD chunk keeps each slice ~5 MB).
//
// XCD-CHUNKED block swizzle kept from R5 (FETCH 49->32.5 MB, real L2 gain):
// logical = (blk&7)*512 + (blk>>3); each XCD owns 128 contiguous rows of one
// batch. Perf heuristic only -- correctness mapping-independent.
//
// s_key padded to [64][K+1]: u64 row stride 72B -> phase-0 write conflict
// drops from 32-way (stride 64B: all lanes in 2 banks) to ~4-way.
// Block = 256 threads handles (b, row h, 64-pixel segment), as before.
// ===========================================================================
__global__ __launch_bounds__(256) void blend_list_kernel(
        const float* __restrict__ pts,
        const float* __restrict__ feat,
        const unsigned int* __restrict__ counts,
        const unsigned long long* __restrict__ lists,
        float* __restrict__ out) {
    int blk = blockIdx.x;                       // 0..4095
    int logical = (blk & 7) * 512 + (blk >> 3); // XCD chunk (4096 % 8 == 0)
    int seg = logical & 3;                      // 0..3  (w segment)
    int h   = (logical >> 2) & 255;             // 0..255
    int b   = logical >> 10;                    // 0..3
    int tid = threadIdx.x;
    int w0  = seg * 64;

    __shared__ float s_alpha[64][K + 1];
    __shared__ float s_wgt[64][K + 1];
    __shared__ int   s_idx[64][K + 1];
    __shared__ int   s_cnt[64];
    __shared__ unsigned long long s_key[64][K + 1];

    const float* pb = pts + (size_t)b * NPTS * 3;

    // Phase 0: wave 0, one pixel per lane; parallel-issue loads + streaming
    // top-8 insertion on named registers.
    if (tid < 64) {
        size_t base = (size_t)b * (S * S) + (size_t)h * S + (size_t)(w0 + tid);
        const ulonglong2* lp2 =
            reinterpret_cast<const ulonglong2*>(lists + base * (size_t)CAP);

        // all 11 loads independent -> single round-trip
        ulonglong2 q0 = lp2[0], q1 = lp2[1], q2 = lp2[2], q3 = lp2[3];
        ulonglong2 q4 = lp2[4], q5 = lp2[5], q6 = lp2[6], q7 = lp2[7];
        ulonglong2 q8 = lp2[8], q9 = lp2[9];
        int c = (int)counts[base];
        if (c > CAP) c = CAP;

        unsigned long long t0 = SENT, t1 = SENT, t2 = SENT, t3 = SENT;
        unsigned long long t4 = SENT, t5 = SENT, t6 = SENT, t7 = SENT;

        PAIR(0, q0); PAIR(1, q1); PAIR(2, q2); PAIR(3, q3); PAIR(4, q4);
        PAIR(5, q5); PAIR(6, q6); PAIR(7, q7); PAIR(8, q8); PAIR(9, q9);

        s_key[tid][0] = t0; s_key[tid][1] = t1;
        s_key[tid][2] = t2; s_key[tid][3] = t3;
        s_key[tid][4] = t4; s_key[tid][5] = t5;
        s_key[tid][6] = t6; s_key[tid][7] = t7;
        s_cnt[tid] = c < K ? c : K;
    }
    __syncthreads();

    // Phase 1: 512 entries, 2 per thread: decode key -> alpha
    for (int e = tid; e < 64 * K; e += 256) {
        int p = e >> 3;
        int k = e & 7;
        unsigned long long key = s_key[p][k];
        float alpha = 0.0f;
        int idx = 0;
        if (key != SENT) {
            idx = (int)(unsigned int)(key & 0xFFFFFFFFULL);
            float x = -pb[(size_t)idx * 3 + 0];
            float y = -pb[(size_t)idx * 3 + 1];
            int w = w0 + p;
            float cy = 1.0f - 2.0f * ((float)h + 0.5f) / 256.0f;
            float cx = 1.0f - 2.0f * ((float)w + 0.5f) / 256.0f;
            float dy = cy - y;
            float dx = cx - x;
            float d2 = dy * dy + dx * dx;
            float dist = d2 / R2;
            dist = fminf(fmaxf(dist, 0.001f), 1.0f);
            alpha = 1.0f - sqrtf(dist);     // gamma = 1 -> **0.5
        }
        s_alpha[p][k] = alpha;
        s_idx[p][k] = idx;
    }
    __syncthreads();

    // Phase 2: exclusive cumprod of (1 - alpha) -> weights
    if (tid < 64) {
        float t = 1.0f;
#pragma unroll
        for (int k = 0; k < K; ++k) {
            float a = s_alpha[tid][k];      // 0 for invalid slots
            s_wgt[tid][k] = a * t;
            t *= (1.0f - a);
        }
    }
    __syncthreads();

    // Phase 3: k-major accumulate, 16 independent gathers per k, unroll 2.
    // Invalid slots gather clamped idx 0 (L1-resident row) with weight 0.
    int wave = tid >> 6;    // 0..3
    int lane = tid & 63;    // channel
    int pbase = wave * 16;

    int kmax = 0;
#pragma unroll
    for (int i = 0; i < 16; ++i) {
        int c = s_cnt[pbase + i];
        kmax = c > kmax ? c : kmax;
    }

    float acc[16];
#pragma unroll
    for (int i = 0; i < 16; ++i) acc[i] = 0.0f;

    const float* fbl = feat + (size_t)b * NPTS * CCH + lane;
#pragma unroll 2
    for (int k = 0; k < kmax; ++k) {
        float v[16];
#pragma unroll
        for (int i = 0; i < 16; ++i) {
            int idx = s_idx[pbase + i][k];          // wave-uniform broadcast
            v[i] = fbl[(size_t)idx << 6];
        }
#pragma unroll
        for (int i = 0; i < 16; ++i) {
            acc[i] += s_wgt[pbase + i][k] * v[i];
        }
    }

    // Phase 4: transposed store, one 64B line per lane (4x float4)
    size_t obase = (((size_t)b * CCH + lane) * S + h) * S + (size_t)(w0 + pbase);
    float4* o4 = (float4*)(out + obase);
#pragma unroll
    for (int q = 0; q < 4; ++q) {
        o4[q] = make_float4(acc[4 * q + 0], acc[4 * q + 1],
                            acc[4 * q + 2], acc[4 * q + 3]);
    }
}

// ===========================================================================
// FALLBACK PATH (unchanged, proven): sorted atomicMin cascade into dense
// per-pixel key slots + original dense blend. Used only if ws_size is too
// small for the append lists.
// ===========================================================================
__global__ __launch_bounds__(256) void scatter_kernel(
        const float* __restrict__ pts,
        unsigned long long* __restrict__ keys) {
    int gid = blockIdx.x * blockDim.x + threadIdx.x;
    if (gid >= BATCH * NPTS * 16) return;
    int cell = gid & 15;
    int pid  = gid >> 4;
    int b = pid / NPTS;
    int n = pid - b * NPTS;

    const float* p = pts + (size_t)pid * 3;
    float x = -p[0];
    float y = -p[1];
    float z = p[2];
    if (!(z >= 0.0f)) return;

    float px = (1.0f - x) * 128.0f - 0.5f;
    float py = (1.0f - y) * 128.0f - 0.5f;
    int cj0 = (int)floorf(px);
    int ci0 = (int)floorf(py);

    int ci = ci0 - 1 + (cell >> 2);
    int cj = cj0 - 1 + (cell & 3);
    if (ci < 0 || ci >= S || cj < 0 || cj >= S) return;

    float cy = 1.0f - 2.0f * ((float)ci + 0.5f) / 256.0f;
    float cx = 1.0f - 2.0f * ((float)cj + 0.5f) / 256.0f;
    float dy = cy - y;
    float dx = cx - x;
    float d2 = dy * dy + dx * dx;
    if (!(d2 <= R2)) return;

    unsigned long long key =
        ((unsigned long long)__float_as_uint(z) << 32) | (unsigned int)n;
    unsigned long long* slot =
        keys + ((size_t)b * S * S + (size_t)(ci * S + cj)) * K;

    if (slot[K - 1] < key) return;

    for (int s = 0; s < K; ++s) {
        if (key == SENT) break;
        unsigned long long old = atomicMin(&slot[s], key);
        key = old > key ? old : key;
    }
}

__global__ __launch_bounds__(256) void blend_kernel(
        const float* __restrict__ pts,
        const float* __restrict__ feat,
        const unsigned long long* __restrict__ keys,
        float* __restrict__ out) {
    int seg = blockIdx.x;
    int h   = blockIdx.y;
    int b   = blockIdx.z;
    int tid = threadIdx.x;
    int w0  = seg * 64;

    __shared__ float s_alpha[64][K + 1];
    __shared__ float s_wgt[64][K + 1];
    __shared__ int   s_idx[64][K + 1];
    __shared__ int   s_cnt[64];

    const unsigned long long* kb =
        keys + ((size_t)b * S * S + (size_t)h * S + w0) * K;
    const float* pb = pts + (size_t)b * NPTS * 3;

    for (int e = tid; e < 64 * K; e += 256) {
        int p = e >> 3;
        int k = e & 7;
        unsigned long long key = kb[(size_t)p * K + k];
        float alpha = 0.0f;
        int idx = -1;
        if (key != SENT) {
            idx = (int)(unsigned int)(key & 0xFFFFFFFFULL);
            float x = -pb[(size_t)idx * 3 + 0];
            float y = -pb[(size_t)idx * 3 + 1];
            int w = w0 + p;
            float cy = 1.0f - 2.0f * ((float)h + 0.5f) / 256.0f;
            float cx = 1.0f - 2.0f * ((float)w + 0.5f) / 256.0f;
            float dy = cy - y;
            float dx = cx - x;
            float d2 = dy * dy + dx * dx;
            float dist = d2 / R2;
            dist = fminf(fmaxf(dist, 0.001f), 1.0f);
            alpha = 1.0f - sqrtf(dist);
        }
        s_alpha[p][k] = alpha;
        s_idx[p][k] = idx;
    }
    __syncthreads();

    if (tid < 64) {
        float t = 1.0f;
        int cnt = 0;
        for (int k = 0; k < K; ++k) {
            int raw = s_idx[tid][k];
            float a = s_alpha[tid][k];
            s_wgt[tid][k] = a * t;
            t *= (1.0f - a);
            if (raw >= 0) cnt = k + 1;
            s_idx[tid][k] = raw < 0 ? 0 : raw;
        }
        s_cnt[tid] = cnt;
    }
    __syncthreads();

    int wave = tid >> 6;
    int lane = tid & 63;
    int pbase = wave * 16;

    int kmax = 0;
#pragma unroll
    for (int i = 0; i < 16; ++i) {
        int c = s_cnt[pbase + i];
        kmax = c > kmax ? c : kmax;
    }

    float acc[16];
#pragma unroll
    for (int i = 0; i < 16; ++i) acc[i] = 0.0f;

    const float* fbl = feat + (size_t)b * NPTS * CCH + lane;
    for (int k = 0; k < kmax; ++k) {
        float v[16];
#pragma unroll
        for (int i = 0; i < 16; ++i) {
            int idx = s_idx[pbase + i][k];
            v[i] = fbl[(size_t)idx << 6];
        }
#pragma unroll
        for (int i = 0; i < 16; ++i) {
            acc[i] += s_wgt[pbase + i][k] * v[i];
        }
    }

    size_t obase = (((size_t)b * CCH + lane) * S + h) * S + (size_t)(w0 + pbase);
    float4* o4 = (float4*)(out + obase);
#pragma unroll
    for (int q = 0; q < 4; ++q) {
        o4[q] = make_float4(acc[4 * q + 0], acc[4 * q + 1],
                            acc[4 * q + 2], acc[4 * q + 3]);
    }
}

extern "C" void kernel_launch(void* const* d_in, const int* in_sizes, int n_in,
                              void* d_out, int out_size, void* d_ws, size_t ws_size,
                              hipStream_t stream) {
    const float* pts  = (const float*)d_in[0];
    const float* feat = (const float*)d_in[1];
    float* out = (float*)d_out;

    size_t cnt_bytes  = (size_t)BATCH * S * S * sizeof(unsigned int);      // 1 MB
    size_t list_bytes = (size_t)BATCH * S * S * CAP * sizeof(unsigned long long); // 42 MB
    size_t key_bytes  = (size_t)BATCH * S * S * K * sizeof(unsigned long long);   // 16.8 MB

    if (ws_size >= cnt_bytes + list_bytes) {
        // list path: 1-atomic scatter -> fused select+blend
        unsigned int* counts = (unsigned int*)d_ws;
        unsigned long long* lists =
            (unsigned long long*)((char*)d_ws + cnt_bytes);
        hipMemsetAsync(counts, 0, cnt_bytes, stream);

        int total = BATCH * NPTS * 16;
        scatter_list_kernel<<<(total + 255) / 256, 256, 0, stream>>>(
            pts, counts, lists);

        blend_list_kernel<<<4096, 256, 0, stream>>>(pts, feat, counts, lists, out);
    } else {
        // fallback: proven sorted-cascade path
        unsigned long long* keys = (unsigned long long*)d_ws;
        hipMemsetAsync(keys, 0xFF, key_bytes, stream);

        int total = BATCH * NPTS * 16;
        scatter_kernel<<<(total + 255) / 256, 256, 0, stream>>>(pts, keys);

        dim3 grid(S / 64, S, BATCH);
        blend_kernel<<<grid, 256, 0, stream>>>(pts, feat, keys, out);
    }
}